// Round 10
// baseline (399.587 us; speedup 1.0000x reference)
//
#include <hip/hip_runtime.h>
#include <hip/hip_bf16.h>
#include <stdint.h>

// ---------------- problem constants ----------------
#define DIMC  512
#define NHEAD 16
#define HDIM  32
#define NTOK  65536          // 4*128*128 tokens
#define QKVN  1536           // 3*DIMC
static constexpr float SCALE_F = 0.17677669529663687f;  // HD^-0.5

typedef __attribute__((ext_vector_type(4))) float  f32x4;
typedef __attribute__((ext_vector_type(8))) __bf16 bf16x8;

__device__ __forceinline__ uint16_t f2bf(float f) {
  union { float f; uint32_t u; } v; v.f = f;
  return (uint16_t)((v.u + 0x7FFFu + ((v.u >> 16) & 1u)) >> 16);
}

// async global->LDS, 16B/lane; LDS dest is wave-uniform base (+lane*16 by HW)
__device__ __forceinline__ void gload_lds16(const void* g, void* l) {
  __builtin_amdgcn_global_load_lds((const __attribute__((address_space(1))) void*)g,
                                   (__attribute__((address_space(3))) void*)l,
                                   16, 0, 0);
}

// ---------------------------------------------------------------------------
// fp32 -> bf16 convert (weights only; x conversion is fused)
// ---------------------------------------------------------------------------
__global__ void cvt_f32_bf16(const float* __restrict__ src,
                             uint16_t* __restrict__ dst, int n4)
{
  int i = blockIdx.x * blockDim.x + threadIdx.x;
  const int stride = gridDim.x * blockDim.x;
  for (; i < n4; i += stride) {
    const float4 v = ((const float4*)src)[i];
    ushort4 o;
    o.x = f2bf(v.x); o.y = f2bf(v.y); o.z = f2bf(v.z); o.w = f2bf(v.w);
    ((ushort4*)dst)[i] = o;
  }
}

// ---------------------------------------------------------------------------
// FUSED x-cvt + QKV GEMM + RoPE + windowed attention.
// One block per attention group g (64 tokens); 8 waves, wave w owns heads
// {2w, 2w+1} sequentially. Eliminates the QKV intermediate (402 MB r+w)
// and the standalone x-cvt kernel (201 MB r+w).
//
// Phase 1 (cooperative): x[64 tok][512] fp32 -> bf16 -> LDS, 16B-unit XOR
//   swizzle (unit u of row r stored at u^(r&7)) -> conflict-free A-frags.
// Phase 2 (per wave, per head): 3x GEMM 64x32x512:
//   A-frag: xs row i*16+lm, k-unit (st*4+lq)^(lm&7)   [proven m97 pattern]
//   B-frag: W^T rows (global bf16, L2-hot): W[(wrow0+j*16+lm)*512 + st*32+lq*8]
//   acc -> per-wave scratch S[64][72] in C-layout (col=lm, row=lq*4+r) + bias.
//   Q/K re-read as frags (lane=token, 8 contig dims) + in-register RoPE
//   (verbatim round-2 attn_win, CPU-verified); V gathered to vf B-frags.
// Phase 3 (per wave): S=QK^T (16 MFMA), wave softmax, P->S, pa frags,
//   PV (16 MFMA), normalize, scatter O.  [verbatim proven attn_win]
// Scratch reuse order per head: Q->qf, K->kf, V->vf (all consumed to regs),
// then P overwrites S. Same-wave LDS ops are program-ordered (may-alias).
// LDS: 64K xs + 72K scr = 139264 B -> 1 block/CU, 2 waves/SIMD.
// ---------------------------------------------------------------------------
__global__ __launch_bounds__(512, 1)
void fused_qkv_attn(const float* __restrict__ x,
                    const uint16_t* __restrict__ Wq,   // qkv_w bf16 [1536][512]
                    const float* __restrict__ qkv_b,   // [1536] fp32
                    uint16_t* __restrict__ O)          // [NTOK][512] bf16
{
  __shared__ __align__(16) __bf16 xs[64][512];     // 64 KiB
  __shared__ __align__(16) __bf16 scr[8][64][72];  // 72 KiB (9216 B/wave)

  const int tid = threadIdx.x;
  const int l  = tid & 63, w = tid >> 6;
  const int lm = l & 15,  lq = l >> 4;
  const int g = blockIdx.x;
  const int d1 = g & 1, d0 = (g >> 1) & 1;
  const int wx = (g >> 2) & 7, wy = (g >> 5) & 7, bb = g >> 8;
  const long tbase = ((long)(bb * 128 + wy * 16 + d0) * 128) + wx * 16 + d1;

  char* xsC = (char*)&xs[0][0];

  // ---- phase 1: stage x (fp32->bf16, swizzled) ----
#pragma unroll
  for (int pass = 0; pass < 8; ++pass) {
    const int G = pass * 512 + tid;
    const int row = G >> 6, u = G & 63;            // 64 units of 16B per row
    const long t = tbase + (row >> 3) * 256 + (row & 7) * 2;
    const float* src = x + t * DIMC + u * 8;
    const f32x4 v0 = *(const f32x4*)src;
    const f32x4 v1 = *(const f32x4*)(src + 4);
    bf16x8 o;
#pragma unroll
    for (int q = 0; q < 4; ++q) { o[q] = (__bf16)v0[q]; o[q + 4] = (__bf16)v1[q]; }
    *(bf16x8*)(xsC + row * 1024 + ((u ^ (row & 7)) << 4)) = o;
  }
  __syncthreads();

  __bf16 (*Sw)[72] = scr[w];                       // per-wave scratch

  f32x4 invs;
#pragma unroll
  for (int i = 0; i < 4; ++i)
    invs[i] = exp2f(-1.6609640474436813f * (float)((lq & 1) * 4 + i));

  const f32x4 fzero = {0.f, 0.f, 0.f, 0.f};

  // per-head 64x32x512 GEMM -> scratch (C-layout + bias)
  auto gemm_to_scr = [&](int wrow0) {
    f32x4 acc[4][2] = {};
    const uint16_t* Wp = Wq + (size_t)wrow0 * DIMC;
#pragma unroll
    for (int st = 0; st < 16; ++st) {
      bf16x8 b[2], a[4];
#pragma unroll
      for (int j = 0; j < 2; ++j)
        b[j] = *(const bf16x8*)(Wp + (size_t)(j * 16 + lm) * DIMC + st * 32 + lq * 8);
#pragma unroll
      for (int i = 0; i < 4; ++i)
        a[i] = *(const bf16x8*)(xsC + (i * 16 + lm) * 1024 +
                                (((st * 4 + lq) ^ (lm & 7)) << 4));
#pragma unroll
      for (int i = 0; i < 4; ++i)
#pragma unroll
        for (int j = 0; j < 2; ++j)
          acc[i][j] = __builtin_amdgcn_mfma_f32_16x16x32_bf16(
              a[i], b[j], acc[i][j], 0, 0, 0);
    }
    const float b0 = qkv_b[wrow0 + lm];
    const float b1 = qkv_b[wrow0 + 16 + lm];
#pragma unroll
    for (int mi = 0; mi < 4; ++mi)
#pragma unroll
      for (int r = 0; r < 4; ++r) {
        Sw[mi * 16 + lq * 4 + r][lm]      = (__bf16)(acc[mi][0][r] + b0);
        Sw[mi * 16 + lq * 4 + r][16 + lm] = (__bf16)(acc[mi][1][r] + b1);
      }
  };

  for (int hp = 0; hp < 2; ++hp) {
    const int h = w * 2 + hp;

    // ---- Q ----
    gemm_to_scr(h * HDIM);
    bf16x8 qf[4], kf[4];
#pragma unroll
    for (int f = 0; f < 4; ++f) {
      const int n = f * 16 + lm, iy = n >> 3, ix = n & 7;
      const float pos = (lq < 2) ? (float)iy : (float)ix;
      bf16x8 raw = *(const bf16x8*)&Sw[n][lq * 8], o;
#pragma unroll
      for (int i = 0; i < 4; ++i) {
        float x1 = (float)raw[2 * i], x2 = (float)raw[2 * i + 1];
        float s_, c_; __sincosf(pos * invs[i], &s_, &c_);
        o[2 * i]     = (__bf16)((x1 * c_ - x2 * s_) * SCALE_F);
        o[2 * i + 1] = (__bf16)((x1 * s_ + x2 * c_) * SCALE_F);
      }
      qf[f] = o;
    }
    // ---- K ----
    gemm_to_scr(DIMC + h * HDIM);
#pragma unroll
    for (int f = 0; f < 4; ++f) {
      const int n = f * 16 + lm, iy = n >> 3, ix = n & 7;
      const float pos = (lq < 2) ? (float)iy : (float)ix;
      bf16x8 raw = *(const bf16x8*)&Sw[n][lq * 8], o;
#pragma unroll
      for (int i = 0; i < 4; ++i) {
        float x1 = (float)raw[2 * i], x2 = (float)raw[2 * i + 1];
        float s_, c_; __sincosf(pos * invs[i], &s_, &c_);
        o[2 * i]     = (__bf16)(x1 * c_ - x2 * s_);
        o[2 * i + 1] = (__bf16)(x1 * s_ + x2 * c_);
      }
      kf[f] = o;
    }
    // ---- V (gather to B-frags: lane = out-dim, k = key-token) ----
    gemm_to_scr(2 * DIMC + h * HDIM);
    bf16x8 vf[2][2];
#pragma unroll
    for (int kk = 0; kk < 2; ++kk)
#pragma unroll
      for (int n2 = 0; n2 < 2; ++n2) {
        bf16x8 o;
#pragma unroll
        for (int i = 0; i < 8; ++i)
          o[i] = Sw[kk * 32 + lq * 8 + i][n2 * 16 + lm];
        vf[kk][n2] = o;
      }

    // ---- S = Q K^T ----
    f32x4 s[4][4];
#pragma unroll
    for (int mi = 0; mi < 4; ++mi)
#pragma unroll
      for (int ni = 0; ni < 4; ++ni)
        s[mi][ni] = __builtin_amdgcn_mfma_f32_16x16x32_bf16(
            qf[mi], kf[ni], fzero, 0, 0, 0);

    // ---- wave softmax (xor-reduce over lm bits) ----
    float rsum[4][4];
#pragma unroll
    for (int mi = 0; mi < 4; ++mi)
#pragma unroll
      for (int r = 0; r < 4; ++r) {
        float m = s[mi][0][r];
#pragma unroll
        for (int ni = 1; ni < 4; ++ni) m = fmaxf(m, s[mi][ni][r]);
        m = fmaxf(m, __shfl_xor(m, 1));
        m = fmaxf(m, __shfl_xor(m, 2));
        m = fmaxf(m, __shfl_xor(m, 4));
        m = fmaxf(m, __shfl_xor(m, 8));
        float sum = 0.f;
#pragma unroll
        for (int ni = 0; ni < 4; ++ni) {
          float p = expf(s[mi][ni][r] - m);
          s[mi][ni][r] = p;
          sum += p;
        }
        sum += __shfl_xor(sum, 1);
        sum += __shfl_xor(sum, 2);
        sum += __shfl_xor(sum, 4);
        sum += __shfl_xor(sum, 8);
        rsum[mi][r] = sum;
      }

    // ---- P -> scratch (C-layout), re-read as A-frags ----
#pragma unroll
    for (int mi = 0; mi < 4; ++mi)
#pragma unroll
      for (int ni = 0; ni < 4; ++ni)
#pragma unroll
        for (int r = 0; r < 4; ++r)
          Sw[mi * 16 + lq * 4 + r][ni * 16 + lm] = (__bf16)s[mi][ni][r];

    bf16x8 pa[4][2];
#pragma unroll
    for (int mi = 0; mi < 4; ++mi)
#pragma unroll
      for (int kk = 0; kk < 2; ++kk)
        pa[mi][kk] = *(const bf16x8*)(&Sw[mi * 16 + lm][kk * 32 + lq * 8]);

    // ---- O = P V ----
    f32x4 oacc[4][2] = {};
#pragma unroll
    for (int kk = 0; kk < 2; ++kk)
#pragma unroll
      for (int mi = 0; mi < 4; ++mi)
#pragma unroll
        for (int n2 = 0; n2 < 2; ++n2)
          oacc[mi][n2] = __builtin_amdgcn_mfma_f32_16x16x32_bf16(
              pa[mi][kk], vf[kk][n2], oacc[mi][n2], 0, 0, 0);

    // ---- normalize + scatter to token order ----
#pragma unroll
    for (int mi = 0; mi < 4; ++mi)
#pragma unroll
      for (int r = 0; r < 4; ++r) {
        const int n = mi * 16 + lq * 4 + r;
        const long t = tbase + (n >> 3) * 256 + (n & 7) * 2;
        const float rinv = 1.0f / rsum[mi][r];
#pragma unroll
        for (int n2 = 0; n2 < 2; ++n2)
          O[t * DIMC + h * HDIM + n2 * 16 + lm] = f2bf(oacc[mi][n2][r] * rinv);
      }
  }
}

// ---------------------------------------------------------------------------
// 256x256 8-phase GEMM (round-7 version, proven) — used for proj only.
// ---------------------------------------------------------------------------
template <bool OUT_F32>
__global__ __launch_bounds__(512, 2)
void gemm256_8ph(const uint16_t* __restrict__ A,
                 const uint16_t* __restrict__ B,
                 const float* __restrict__ bias,
                 void* __restrict__ Cv,
                 int M, int N, int K, int gx)
{
  __shared__ __align__(16) char lds[131072];

  const int tid = threadIdx.x;
  const int l  = tid & 63, w = tid >> 6;
  const int wm = w >> 2,  wn = w & 3;
  const int lm = l & 15,  lq = l >> 4;

  const int nwg = gridDim.x;
  const int qq = nwg >> 3, rr = nwg & 7;
  const int xcd = blockIdx.x & 7, loc = blockIdx.x >> 3;
  const int sw = (xcd < rr ? xcd * (qq + 1) : rr * (qq + 1) + (xcd - rr) * qq) + loc;
  const long m0 = (long)(sw / gx) * 256;
  const long n0 = (long)(sw % gx) * 256;

  const int srow  = tid >> 3;
  const int scolb = (((tid & 7) ^ (srow & 7)) << 4);
  const uint16_t* Ags = A + (m0 + srow) * (long)K + (scolb >> 1);
  const uint16_t* Bgs = B + (n0 + srow) * (long)K + (scolb >> 1);
  char* ldsW = lds + (w << 10);

#define STAGE(Gs, regionOff, half, kt)                                        \
  {                                                                           \
    const uint16_t* s0_ = (Gs) + (size_t)((half) * 128) * K + (kt);           \
    gload_lds16(s0_,                  ldsW + (regionOff));                    \
    gload_lds16(s0_ + (size_t)64 * K, ldsW + (regionOff) + 8192);             \
  }

  const int colx0 = ((lq ^ (lm & 7)) << 4);
  const int aoff0 = (wm * 64 + lm) * 128 + colx0;
  const int aoff1 = (wm * 64 + lm) * 128 + (colx0 ^ 64);
  const int boff0 = (wn * 32 + lm) * 128 + colx0;
  const int boff1 = (wn * 32 + lm) * 128 + (colx0 ^ 64);

  f32x4  acc[2][2][4][2] = {};
  bf16x8 aX[4][2], aY[4][2];
  bf16x8 b0[2][2], b1[2][2];

#define RD_A(DST, OFF)                                                        \
  _Pragma("unroll") for (int i = 0; i < 4; ++i) {                             \
    DST[i][0] = *(const bf16x8*)(lds + (OFF) + aoff0 + i * 2048);             \
    DST[i][1] = *(const bf16x8*)(lds + (OFF) + aoff1 + i * 2048);             \
  }
#define RD_B(DST, OFF)                                                        \
  _Pragma("unroll") for (int j = 0; j < 2; ++j) {                             \
    DST[j][0] = *(const bf16x8*)(lds + (OFF) + boff0 + j * 2048);             \
    DST[j][1] = *(const bf16x8*)(lds + (OFF) + boff1 + j * 2048);             \
  }
#define MFMA16(AS, BS, QM, QN)                                                \
  __builtin_amdgcn_s_setprio(1);                                              \
  _Pragma("unroll") for (int kk = 0; kk < 2; ++kk)                            \
    _Pragma("unroll") for (int i = 0; i < 4; ++i)                             \
      _Pragma("unroll") for (int j = 0; j < 2; ++j)                           \
        acc[QM][QN][i][j] = __builtin_amdgcn_mfma_f32_16x16x32_bf16(          \
            AS[i][kk], BS[j][kk], acc[QM][QN][i][j], 0, 0, 0);                \
  __builtin_amdgcn_s_setprio(0);
#define VMW(N) asm volatile("s_waitcnt vmcnt(" #N ")");
#define BAR()  __builtin_amdgcn_s_barrier();

  STAGE(Ags, 0,             0, 0)
  STAGE(Bgs, 32768,         0, 0)
  STAGE(Ags, 16384,         1, 0)
  STAGE(Bgs, 49152,         1, 0)
  STAGE(Ags, 65536,         0, 64)
  STAGE(Bgs, 65536 + 32768, 0, 64)
  VMW(8) BAR()
  RD_A(aX, 0) RD_B(b0, 32768)
  VMW(4) BAR()

  for (int t2 = 0; t2 < K / 64; t2 += 2) {
    const int k1 = (t2 + 1) * 64;
    int k2 = (t2 + 2) * 64; if (k2 >= K) k2 = 0;
    int k3 = (t2 + 3) * 64; if (k3 >= K) k3 = 0;

    RD_B(b1, 49152)                 STAGE(Ags, 65536 + 16384, 1, k1)
    MFMA16(aX, b0, 0, 0)            BAR()
    RD_A(aY, 16384)                 STAGE(Bgs, 65536 + 49152, 1, k1)
    MFMA16(aX, b1, 0, 1)            BAR()
    STAGE(Ags, 0, 0, k2)
    MFMA16(aY, b0, 1, 0)            VMW(6) BAR()
    RD_A(aX, 65536) RD_B(b0, 65536 + 32768)
    STAGE(Bgs, 32768, 0, k2)
    MFMA16(aY, b1, 1, 1)            VMW(4) BAR()
    RD_B(b1, 65536 + 49152)         STAGE(Ags, 16384, 1, k2)
    MFMA16(aX, b0, 0, 0)            BAR()
    RD_A(aY, 65536 + 16384)         STAGE(Bgs, 49152, 1, k2)
    MFMA16(aX, b1, 0, 1)            BAR()
    STAGE(Ags, 65536, 0, k3)
    MFMA16(aY, b0, 1, 0)            VMW(6) BAR()
    RD_A(aX, 0) RD_B(b0, 32768)
    STAGE(Bgs, 65536 + 32768, 0, k3)
    MFMA16(aY, b1, 1, 1)            VMW(4) BAR()
  }
#undef STAGE
#undef RD_A
#undef RD_B
#undef MFMA16
#undef VMW
#undef BAR

#pragma unroll
  for (int qm = 0; qm < 2; ++qm)
#pragma unroll
  for (int qn = 0; qn < 2; ++qn)
#pragma unroll
  for (int i = 0; i < 4; ++i)
#pragma unroll
  for (int j = 0; j < 2; ++j) {
    const long m = m0 + qm * 128 + wm * 64 + i * 16 + lq * 4;
    const long n = n0 + qn * 128 + wn * 32 + j * 16 + lm;
    const float bv = bias[n];
#pragma unroll
    for (int r = 0; r < 4; ++r) {
      const float val = acc[qm][qn][i][j][r] + bv;
      if (OUT_F32) ((float*)Cv)[(m + r) * (long)N + n] = val;
      else         ((uint16_t*)Cv)[(m + r) * (long)N + n] = f2bf(val);
    }
  }
}

// ---------------------------------------------------------------------------
extern "C" void kernel_launch(void* const* d_in, const int* in_sizes, int n_in,
                              void* d_out, int out_size, void* d_ws, size_t ws_size,
                              hipStream_t stream)
{
  const float* x      = (const float*)d_in[0];   // [65536][512] fp32
  const float* qkv_w  = (const float*)d_in[1];   // [1536][512]  fp32
  const float* qkv_b  = (const float*)d_in[2];   // [1536]       fp32
  const float* proj_w = (const float*)d_in[3];   // [512][512]   fp32
  const float* proj_b = (const float*)d_in[4];   // [512]        fp32
  float* out = (float*)d_out;                    // [65536][512] fp32

  uint16_t* qwb  = (uint16_t*)d_ws;                      // 1.5 MiB
  uint16_t* pwb  = qwb + (size_t)QKVN * DIMC;            // 0.5 MiB
  uint16_t* attn = pwb + (size_t)DIMC * DIMC;            // 64 MiB

  // 0) weight fp32 -> bf16
  cvt_f32_bf16<<<512, 256, 0, stream>>>(qkv_w,  qwb, QKVN * DIMC / 4);
  cvt_f32_bf16<<<256, 256, 0, stream>>>(proj_w, pwb, DIMC * DIMC / 4);

  // 1) fused x-cvt + QKV + RoPE + attention (1024 groups)
  fused_qkv_attn<<<dim3(1024), dim3(512), 0, stream>>>(x, qwb, qkv_b, attn);

  // 2) out = attn @ proj_w^T + proj_b  (fp32 out)
  gemm256_8ph<true><<<dim3((NTOK / 256) * (DIMC / 256)), dim3(512), 0, stream>>>(
      attn, pwb, proj_b, out, NTOK, DIMC, DIMC, DIMC / 256);
}